// Round 2
// baseline (449.050 us; speedup 1.0000x reference)
//
#include <hip/hip_runtime.h>

// Problem constants
#define NH 16
#define HD 64
#define CE 1024
#define TT 2048
#define BB 4
#define MM 8192   // B*T

using bf16x8 = __attribute__((ext_vector_type(8))) __bf16;
using f32x4  = __attribute__((ext_vector_type(4))) float;

__device__ __forceinline__ unsigned short f2bf(float f) {
  unsigned int u = __float_as_uint(f);
  u += 0x7fffu + ((u >> 16) & 1u);   // RNE
  return (unsigned short)(u >> 16);
}

// ---------------- fp32 -> bf16 convert (x) ----------------
__global__ __launch_bounds__(256) void convert_x(const float* __restrict__ in,
                                                 unsigned short* __restrict__ out) {
  const int i = (blockIdx.x * 256 + threadIdx.x) * 4;
  const float4 v = *(const float4*)(in + i);
  ushort4 o;
  o.x = f2bf(v.x); o.y = f2bf(v.y); o.z = f2bf(v.z); o.w = f2bf(v.w);
  *(ushort4*)(out + i) = o;
}

// ------------- transpose + fp32->bf16: in[rows][cols] f32 -> out[cols][rows] bf16 -------------
__global__ __launch_bounds__(256) void transpose_conv(const float* __restrict__ in,
                                                      unsigned short* __restrict__ out,
                                                      int rows, int cols) {
  __shared__ unsigned short tile[32][33];
  int c0 = blockIdx.x * 32, r0 = blockIdx.y * 32;
  int tx = threadIdx.x & 31, ty = threadIdx.x >> 5;  // ty 0..7
#pragma unroll
  for (int i = ty; i < 32; i += 8)
    tile[i][tx] = f2bf(in[(size_t)(r0 + i) * cols + c0 + tx]);
  __syncthreads();
#pragma unroll
  for (int i = ty; i < 32; i += 8)
    out[(size_t)(c0 + i) * rows + r0 + tx] = tile[tx][i];
}

// ---------------- GEMM core: C[128x128] tile of A[M,1024] @ BT[N,1024]^T ----------------
// block = 256 threads = 4 waves; wave computes 64x64 as 4x4 grid of 16x16x32 MFMAs.
__device__ __forceinline__ void gemm_core(const unsigned short* __restrict__ A,
                                          const unsigned short* __restrict__ BT,
                                          int m0, int n0, f32x4 (&acc)[4][4]) {
  __shared__ unsigned short As[128][40];  // +8 pad: 80B stride -> 2-way bank alias (free)
  __shared__ unsigned short Bs[128][40];
  const int tid  = threadIdx.x;
  const int lane = tid & 63;
  const int wave = tid >> 6;
  const int quad = lane >> 4;
  const int l15  = lane & 15;
  const int wm = (wave & 1) * 64;
  const int wn = (wave >> 1) * 64;
  const int ldr = tid >> 2;         // 0..63
  const int ldc = (tid & 3) * 8;    // 0,8,16,24
  const unsigned short* Ap = A + (size_t)(m0 + ldr) * CE + ldc;
  const unsigned short* Bp = BT + (size_t)(n0 + ldr) * CE + ldc;
  for (int k0 = 0; k0 < CE; k0 += 32) {
    *(uint4*)&As[ldr][ldc]      = *(const uint4*)(Ap + k0);
    *(uint4*)&As[ldr + 64][ldc] = *(const uint4*)(Ap + (size_t)64 * CE + k0);
    *(uint4*)&Bs[ldr][ldc]      = *(const uint4*)(Bp + k0);
    *(uint4*)&Bs[ldr + 64][ldc] = *(const uint4*)(Bp + (size_t)64 * CE + k0);
    __syncthreads();
    bf16x8 af[4], bfr[4];
#pragma unroll
    for (int i = 0; i < 4; i++) {
      af[i]  = *(const bf16x8*)&As[wm + i * 16 + l15][quad * 8];
      bfr[i] = *(const bf16x8*)&Bs[wn + i * 16 + l15][quad * 8];
    }
#pragma unroll
    for (int mi = 0; mi < 4; mi++)
#pragma unroll
      for (int ni = 0; ni < 4; ni++)
        acc[mi][ni] = __builtin_amdgcn_mfma_f32_16x16x32_bf16(af[mi], bfr[ni], acc[mi][ni], 0, 0, 0);
    __syncthreads();
  }
}

// ---------------- GEMM 1: qkv = x @ w_qkv, scattered into Q (scaled), K, V^T ----------------
__global__ __launch_bounds__(256) void gemm_qkv(const unsigned short* __restrict__ A,
                                                const unsigned short* __restrict__ BT,
                                                unsigned short* __restrict__ Qb,
                                                unsigned short* __restrict__ Kb,
                                                unsigned short* __restrict__ Vtb) {
  f32x4 acc[4][4] = {};
  const int m0 = blockIdx.y * 128, n0 = blockIdx.x * 128;
  gemm_core(A, BT, m0, n0, acc);
  const int tid = threadIdx.x, lane = tid & 63, wave = tid >> 6;
  const int quad = lane >> 4, l15 = lane & 15;
  const int wm = (wave & 1) * 64, wn = (wave >> 1) * 64;
#pragma unroll
  for (int mi = 0; mi < 4; mi++) {
#pragma unroll
    for (int ni = 0; ni < 4; ni++) {
      const int n = n0 + wn + ni * 16 + l15;
      const int s = n >> 10;           // 0=q 1=k 2=v
      const int h = (n >> 6) & 15;
      const int d = n & 63;
#pragma unroll
      for (int r = 0; r < 4; r++) {
        const int m = m0 + wm + mi * 16 + quad * 4 + r;
        const int b = m >> 11;         // /2048
        const int t = m & 2047;
        const int bh = (b << 4) + h;
        const float v = acc[mi][ni][r];
        if (s == 0)      Qb [((size_t)bh * TT + t) * HD + d] = f2bf(v * 0.125f);
        else if (s == 1) Kb [((size_t)bh * TT + t) * HD + d] = f2bf(v);
        else             Vtb[((size_t)bh * HD + d) * TT + t] = f2bf(v);
      }
    }
  }
}

// ---------------- GEMM 2: out = AO @ w_out + b_out (fp32 out) ----------------
__global__ __launch_bounds__(256) void gemm_out(const unsigned short* __restrict__ A,
                                                const unsigned short* __restrict__ BT,
                                                const float* __restrict__ bias,
                                                float* __restrict__ out) {
  f32x4 acc[4][4] = {};
  const int m0 = blockIdx.y * 128, n0 = blockIdx.x * 128;
  gemm_core(A, BT, m0, n0, acc);
  const int tid = threadIdx.x, lane = tid & 63, wave = tid >> 6;
  const int quad = lane >> 4, l15 = lane & 15;
  const int wm = (wave & 1) * 64, wn = (wave >> 1) * 64;
#pragma unroll
  for (int mi = 0; mi < 4; mi++) {
#pragma unroll
    for (int ni = 0; ni < 4; ni++) {
      const int n = n0 + wn + ni * 16 + l15;
      const float bv = bias[n];
#pragma unroll
      for (int r = 0; r < 4; r++) {
        const int m = m0 + wm + mi * 16 + quad * 4 + r;
        out[(size_t)m * CE + n] = acc[mi][ni][r] + bv;
      }
    }
  }
}

// ---------------- causal flash attention ----------------
// grid: (T/64, B*H); block 256 = 4 waves; wave w owns Q rows q0+w*16 .. +15.
// Q,K: [BH][T][64]; Vt: [BH][64][T]; AO: [B*T][1024] (col = h*64+d)
__global__ __launch_bounds__(256) void flash_attn(const unsigned short* __restrict__ Q,
                                                  const unsigned short* __restrict__ Kg,
                                                  const unsigned short* __restrict__ Vt,
                                                  unsigned short* __restrict__ AO) {
  __shared__ unsigned short Ks[64][72];     // [kv][d], pad->2-way alias free
  __shared__ unsigned short Vs[64][72];     // [d][kv]
  __shared__ unsigned short Ps[4][16][72];  // per-wave P, [qrow][kv]
  const int bh = blockIdx.y;
  const int q0 = blockIdx.x * 64;
  const int tid = threadIdx.x, w = tid >> 6, lane = tid & 63;
  const int quad = lane >> 4, l15 = lane & 15;
  const int b = bh >> 4, h = bh & 15;
  // Q fragments (loop-invariant): A[m=l15][k=quad*8+j (+32)]
  const unsigned short* Qp = Q + ((size_t)bh * TT + q0 + w * 16 + l15) * HD + quad * 8;
  const bf16x8 qf0 = *(const bf16x8*)Qp;
  const bf16x8 qf1 = *(const bf16x8*)(Qp + 32);
  float m_i[4], l_i[4], alpha[4];
  f32x4 o[4] = {};
#pragma unroll
  for (int r = 0; r < 4; r++) { m_i[r] = -1e30f; l_i[r] = 0.f; }
  const unsigned short* Kbase = Kg + (size_t)bh * TT * HD;
  const unsigned short* Vbase = Vt + (size_t)bh * HD * TT;
  const int sr = tid >> 3;        // 0..31
  const int sc = (tid & 7) * 8;   // 0..56
  const int n_tiles = (q0 >> 6) + 1;
  for (int it = 0; it < n_tiles; it++) {
    const int kv0 = it * 64;
    __syncthreads();  // previous iteration's LDS reads done
    *(uint4*)&Ks[sr][sc]      = *(const uint4*)(Kbase + (size_t)(kv0 + sr) * HD + sc);
    *(uint4*)&Ks[sr + 32][sc] = *(const uint4*)(Kbase + (size_t)(kv0 + sr + 32) * HD + sc);
    *(uint4*)&Vs[sr][sc]      = *(const uint4*)(Vbase + (size_t)sr * TT + kv0 + sc);
    *(uint4*)&Vs[sr + 32][sc] = *(const uint4*)(Vbase + (size_t)(sr + 32) * TT + kv0 + sc);
    __syncthreads();
    // S = Q K^T : D[row=qrow(quad*4+reg)][col=kv(l15)] per 16-col tile
    f32x4 s[4];
#pragma unroll
    for (int ni = 0; ni < 4; ni++) {
      const bf16x8 kb0 = *(const bf16x8*)&Ks[ni * 16 + l15][quad * 8];
      const bf16x8 kb1 = *(const bf16x8*)&Ks[ni * 16 + l15][32 + quad * 8];
      f32x4 z = {};
      z = __builtin_amdgcn_mfma_f32_16x16x32_bf16(qf0, kb0, z, 0, 0, 0);
      z = __builtin_amdgcn_mfma_f32_16x16x32_bf16(qf1, kb1, z, 0, 0, 0);
      s[ni] = z;
    }
    // online softmax (per q-row; cols spread over the 16 lanes of a quad-row group)
#pragma unroll
    for (int r = 0; r < 4; r++) {
      const int row_g = q0 + w * 16 + quad * 4 + r;
      float mx = -1e30f;
#pragma unroll
      for (int ni = 0; ni < 4; ni++) {
        const int col_g = kv0 + ni * 16 + l15;
        float sv = s[ni][r];
        sv = (col_g <= row_g) ? sv : -1e30f;
        s[ni][r] = sv;
        mx = fmaxf(mx, sv);
      }
      mx = fmaxf(mx, __shfl_xor(mx, 1));
      mx = fmaxf(mx, __shfl_xor(mx, 2));
      mx = fmaxf(mx, __shfl_xor(mx, 4));
      mx = fmaxf(mx, __shfl_xor(mx, 8));
      const float mnew = fmaxf(m_i[r], mx);
      alpha[r] = __expf(m_i[r] - mnew);
      m_i[r] = mnew;
      float rs = 0.f;
#pragma unroll
      for (int ni = 0; ni < 4; ni++) {
        const float p = __expf(s[ni][r] - mnew);
        s[ni][r] = p;
        rs += p;
      }
      rs += __shfl_xor(rs, 1);
      rs += __shfl_xor(rs, 2);
      rs += __shfl_xor(rs, 4);
      rs += __shfl_xor(rs, 8);
      l_i[r] = l_i[r] * alpha[r] + rs;
    }
    // P: MFMA C-layout -> LDS -> A-layout (verified m120 transform)
#pragma unroll
    for (int ni = 0; ni < 4; ni++)
#pragma unroll
      for (int r = 0; r < 4; r++)
        Ps[w][quad * 4 + r][ni * 16 + l15] = f2bf(s[ni][r]);
    __syncthreads();
    // rescale O by alpha (row = quad*4+reg)
#pragma unroll
    for (int nd = 0; nd < 4; nd++)
#pragma unroll
      for (int r = 0; r < 4; r++)
        o[nd][r] *= alpha[r];
    // O += P @ V : A[m=qrow][k=kv], B[k=kv][n=d]
    const bf16x8 pa0 = *(const bf16x8*)&Ps[w][l15][quad * 8];
    const bf16x8 pa1 = *(const bf16x8*)&Ps[w][l15][32 + quad * 8];
#pragma unroll
    for (int nd = 0; nd < 4; nd++) {
      const bf16x8 vb0 = *(const bf16x8*)&Vs[nd * 16 + l15][quad * 8];
      const bf16x8 vb1 = *(const bf16x8*)&Vs[nd * 16 + l15][32 + quad * 8];
      o[nd] = __builtin_amdgcn_mfma_f32_16x16x32_bf16(pa0, vb0, o[nd], 0, 0, 0);
      o[nd] = __builtin_amdgcn_mfma_f32_16x16x32_bf16(pa1, vb1, o[nd], 0, 0, 0);
    }
  }
  // epilogue: normalize and write [B,T,H*D]
#pragma unroll
  for (int nd = 0; nd < 4; nd++)
#pragma unroll
    for (int r = 0; r < 4; r++) {
      const int row_g = q0 + w * 16 + quad * 4 + r;
      const size_t mg = (size_t)b * TT + row_g;
      AO[mg * CE + h * 64 + nd * 16 + l15] = f2bf(o[nd][r] / l_i[r]);
    }
}

extern "C" void kernel_launch(void* const* d_in, const int* in_sizes, int n_in,
                              void* d_out, int out_size, void* d_ws, size_t ws_size,
                              hipStream_t stream) {
  const float* x     = (const float*)d_in[0];  // [4,2048,1024] f32
  const float* w_qkv = (const float*)d_in[1];  // [1024,3072] f32
  const float* w_out = (const float*)d_in[2];  // [1024,1024] f32
  const float* b_out = (const float*)d_in[3];  // [1024] f32
  float* out = (float*)d_out;                  // [4,2048,1024] f32

  unsigned short* ws  = (unsigned short*)d_ws;
  unsigned short* Xb  = ws;                                  // x bf16 [8192][1024]
  unsigned short* Wt1 = Xb  + (size_t)MM * CE;               // w_qkv^T  [3072][1024]
  unsigned short* Wt2 = Wt1 + (size_t)3072 * 1024;           // w_out^T  [1024][1024]
  unsigned short* Qb  = Wt2 + (size_t)1024 * 1024;           // [BH][T][64]
  unsigned short* Kb  = Qb  + (size_t)8388608;               // [BH][T][64]
  unsigned short* Vtb = Kb  + (size_t)8388608;               // [BH][64][T]
  unsigned short* AO  = Vtb + (size_t)8388608;               // [M][1024] bf16

  convert_x     <<<dim3(8192), 256, 0, stream>>>(x, Xb);
  transpose_conv<<<dim3(96, 32), 256, 0, stream>>>(w_qkv, Wt1, 1024, 3072);
  transpose_conv<<<dim3(32, 32), 256, 0, stream>>>(w_out, Wt2, 1024, 1024);
  gemm_qkv  <<<dim3(24, 64), 256, 0, stream>>>(Xb, Wt1, Qb, Kb, Vtb);
  flash_attn<<<dim3(32, 64), 256, 0, stream>>>(Qb, Kb, Vtb, AO);
  gemm_out  <<<dim3(8, 64), 256, 0, stream>>>(AO, Wt2, b_out, out);
}

// Round 3
// 344.744 us; speedup vs baseline: 1.3026x; 1.3026x over previous
//
#include <hip/hip_runtime.h>

// Problem constants
#define NH 16
#define HD 64
#define CE 1024
#define TT 2048
#define BB 4
#define MM 8192   // B*T

using bf16x8 = __attribute__((ext_vector_type(8))) __bf16;
using f32x4  = __attribute__((ext_vector_type(4))) float;

__device__ __forceinline__ unsigned short f2bf(float f) {
  unsigned int u = __float_as_uint(f);
  u += 0x7fffu + ((u >> 16) & 1u);   // RNE
  return (unsigned short)(u >> 16);
}

// async global->LDS, 16B per lane; LDS dst must be wave-uniform (HW adds lane*16)
__device__ __forceinline__ void async_cp16(const unsigned short* g, unsigned short* l) {
  __builtin_amdgcn_global_load_lds(
      (const __attribute__((address_space(1))) unsigned int*)g,
      (__attribute__((address_space(3))) unsigned int*)l, 16, 0, 0);
}

// ---------------- fp32 -> bf16 convert (x) ----------------
__global__ __launch_bounds__(256) void convert_x(const float* __restrict__ in,
                                                 unsigned short* __restrict__ out) {
  const int i = (blockIdx.x * 256 + threadIdx.x) * 4;
  const float4 v = *(const float4*)(in + i);
  ushort4 o;
  o.x = f2bf(v.x); o.y = f2bf(v.y); o.z = f2bf(v.z); o.w = f2bf(v.w);
  *(ushort4*)(out + i) = o;
}

// ------------- transpose + fp32->bf16: in[rows][cols] f32 -> out[cols][rows] bf16 -------------
__global__ __launch_bounds__(256) void transpose_conv(const float* __restrict__ in,
                                                      unsigned short* __restrict__ out,
                                                      int rows, int cols) {
  __shared__ unsigned short tile[32][33];
  int c0 = blockIdx.x * 32, r0 = blockIdx.y * 32;
  int tx = threadIdx.x & 31, ty = threadIdx.x >> 5;  // ty 0..7
#pragma unroll
  for (int i = ty; i < 32; i += 8)
    tile[i][tx] = f2bf(in[(size_t)(r0 + i) * cols + c0 + tx]);
  __syncthreads();
#pragma unroll
  for (int i = ty; i < 32; i += 8)
    out[(size_t)(c0 + i) * rows + r0 + tx] = tile[tx][i];
}

// ---------------- GEMM core (m97 structure): C[128x128] tile of A[M,1024] @ BT[N,1024]^T --------
// block = 256 threads = 4 waves; wave computes 64x64 as 4x4 grid of 16x16x32 MFMAs.
// LDS unpadded [128][32] so global_load_lds lane order (lane*16B) matches layout:
// linear elem offset tid*8  <=>  row=tid>>2, col=(tid&3)*8.
__device__ __forceinline__ void gemm_core(const unsigned short* __restrict__ A,
                                          const unsigned short* __restrict__ BT,
                                          int m0, int n0, f32x4 (&acc)[4][4]) {
  __shared__ unsigned short As[128 * 32];
  __shared__ unsigned short Bs[128 * 32];
  const int tid  = threadIdx.x;
  const int lane = tid & 63;
  const int wave = tid >> 6;
  const int quad = lane >> 4;
  const int l15  = lane & 15;
  const int wm = (wave & 1) * 64;
  const int wn = (wave >> 1) * 64;
  const int ldr = tid >> 2;         // 0..63
  const int ldc = (tid & 3) * 8;    // 0,8,16,24
  const unsigned short* Ap = A + (size_t)(m0 + ldr) * CE + ldc;
  const unsigned short* Bp = BT + (size_t)(n0 + ldr) * CE + ldc;
  unsigned short* AsW0 = As + wave * 512;          // wave-uniform LDS dst, rows 0..63
  unsigned short* AsW1 = As + 2048 + wave * 512;   // rows 64..127
  unsigned short* BsW0 = Bs + wave * 512;
  unsigned short* BsW1 = Bs + 2048 + wave * 512;
  for (int k0 = 0; k0 < CE; k0 += 32) {
    async_cp16(Ap + k0, AsW0);
    async_cp16(Ap + (size_t)64 * CE + k0, AsW1);
    async_cp16(Bp + k0, BsW0);
    async_cp16(Bp + (size_t)64 * CE + k0, BsW1);
    __syncthreads();   // compiler emits vmcnt(0) drain before barrier
    bf16x8 af[4], bfr[4];
#pragma unroll
    for (int i = 0; i < 4; i++) {
      af[i]  = *(const bf16x8*)&As[(wm + i * 16 + l15) * 32 + quad * 8];
      bfr[i] = *(const bf16x8*)&Bs[(wn + i * 16 + l15) * 32 + quad * 8];
    }
#pragma unroll
    for (int mi = 0; mi < 4; mi++)
#pragma unroll
      for (int ni = 0; ni < 4; ni++)
        acc[mi][ni] = __builtin_amdgcn_mfma_f32_16x16x32_bf16(af[mi], bfr[ni], acc[mi][ni], 0, 0, 0);
    __syncthreads();
  }
}

// ---------------- GEMM 1: qkv = x @ w_qkv, scattered into Q (scaled), K, V^T ----------------
__global__ __launch_bounds__(256) void gemm_qkv(const unsigned short* __restrict__ A,
                                                const unsigned short* __restrict__ BT,
                                                unsigned short* __restrict__ Qb,
                                                unsigned short* __restrict__ Kb,
                                                unsigned short* __restrict__ Vtb) {
  f32x4 acc[4][4] = {};
  const int m0 = blockIdx.y * 128, n0 = blockIdx.x * 128;
  gemm_core(A, BT, m0, n0, acc);
  const int tid = threadIdx.x, lane = tid & 63, wave = tid >> 6;
  const int quad = lane >> 4, l15 = lane & 15;
  const int wm = (wave & 1) * 64, wn = (wave >> 1) * 64;
#pragma unroll
  for (int mi = 0; mi < 4; mi++) {
#pragma unroll
    for (int ni = 0; ni < 4; ni++) {
      const int n = n0 + wn + ni * 16 + l15;
      const int s = n >> 10;           // 0=q 1=k 2=v
      const int h = (n >> 6) & 15;
      const int d = n & 63;
#pragma unroll
      for (int r = 0; r < 4; r++) {
        const int m = m0 + wm + mi * 16 + quad * 4 + r;
        const int b = m >> 11;         // /2048
        const int t = m & 2047;
        const int bh = (b << 4) + h;
        const float v = acc[mi][ni][r];
        if (s == 0)      Qb [((size_t)bh * TT + t) * HD + d] = f2bf(v * 0.125f);
        else if (s == 1) Kb [((size_t)bh * TT + t) * HD + d] = f2bf(v);
        else             Vtb[((size_t)bh * HD + d) * TT + t] = f2bf(v);
      }
    }
  }
}

// ---------------- GEMM 2: out = AO @ w_out + b_out (fp32 out) ----------------
__global__ __launch_bounds__(256) void gemm_out(const unsigned short* __restrict__ A,
                                                const unsigned short* __restrict__ BT,
                                                const float* __restrict__ bias,
                                                float* __restrict__ out) {
  f32x4 acc[4][4] = {};
  const int m0 = blockIdx.y * 128, n0 = blockIdx.x * 128;
  gemm_core(A, BT, m0, n0, acc);
  const int tid = threadIdx.x, lane = tid & 63, wave = tid >> 6;
  const int quad = lane >> 4, l15 = lane & 15;
  const int wm = (wave & 1) * 64, wn = (wave >> 1) * 64;
#pragma unroll
  for (int mi = 0; mi < 4; mi++) {
#pragma unroll
    for (int ni = 0; ni < 4; ni++) {
      const int n = n0 + wn + ni * 16 + l15;
      const float bv = bias[n];
#pragma unroll
      for (int r = 0; r < 4; r++) {
        const int m = m0 + wm + mi * 16 + quad * 4 + r;
        out[(size_t)m * CE + n] = acc[mi][ni][r] + bv;
      }
    }
  }
}

// ---------------- causal flash attention, balanced pairing ----------------
// grid: (T/128 = 16, B*H); block handles q-tiles p=blockIdx.x and 31-p -> 33 KV iters always.
// block 256 = 4 waves; wave w owns Q rows q0+w*16 .. +15.
// Q,K: [BH][T][64]; Vt: [BH][64][T]; AO: [B*T][1024] (col = h*64+d)
__global__ __launch_bounds__(256) void flash_attn(const unsigned short* __restrict__ Q,
                                                  const unsigned short* __restrict__ Kg,
                                                  const unsigned short* __restrict__ Vt,
                                                  unsigned short* __restrict__ AO) {
  __shared__ unsigned short Ks[64][72];     // [kv][d], pad->2-way alias free
  __shared__ unsigned short Vs[64][72];     // [d][kv]
  __shared__ unsigned short Ps[4][16][72];  // per-wave P, [qrow][kv]
  const int bh = blockIdx.y;
  const int tid = threadIdx.x, w = tid >> 6, lane = tid & 63;
  const int quad = lane >> 4, l15 = lane & 15;
  const int b = bh >> 4, h = bh & 15;
  const unsigned short* Kbase = Kg + (size_t)bh * TT * HD;
  const unsigned short* Vbase = Vt + (size_t)bh * HD * TT;
  const int sr = tid >> 3;        // 0..31
  const int sc = (tid & 7) * 8;   // 0..56

  for (int ph = 0; ph < 2; ph++) {
    const int p  = ph ? (31 - blockIdx.x) : blockIdx.x;
    const int q0 = p * 64;
    // Q fragments (phase-invariant): A[m=l15][k=quad*8+j (+32)]
    const unsigned short* Qp = Q + ((size_t)bh * TT + q0 + w * 16 + l15) * HD + quad * 8;
    const bf16x8 qf0 = *(const bf16x8*)Qp;
    const bf16x8 qf1 = *(const bf16x8*)(Qp + 32);
    float m_i[4], l_i[4], alpha[4];
    f32x4 o[4] = {};
#pragma unroll
    for (int r = 0; r < 4; r++) { m_i[r] = -1e30f; l_i[r] = 0.f; }

    for (int it = 0; it <= p; it++) {
      const int kv0 = it * 64;
      __syncthreads();  // previous iteration's (or phase's) LDS reads done
      *(uint4*)&Ks[sr][sc]      = *(const uint4*)(Kbase + (size_t)(kv0 + sr) * HD + sc);
      *(uint4*)&Ks[sr + 32][sc] = *(const uint4*)(Kbase + (size_t)(kv0 + sr + 32) * HD + sc);
      *(uint4*)&Vs[sr][sc]      = *(const uint4*)(Vbase + (size_t)sr * TT + kv0 + sc);
      *(uint4*)&Vs[sr + 32][sc] = *(const uint4*)(Vbase + (size_t)(sr + 32) * TT + kv0 + sc);
      __syncthreads();
      // S = Q K^T : D[row=qrow(quad*4+reg)][col=kv(l15)] per 16-col tile
      f32x4 s[4];
#pragma unroll
      for (int ni = 0; ni < 4; ni++) {
        const bf16x8 kb0 = *(const bf16x8*)&Ks[ni * 16 + l15][quad * 8];
        const bf16x8 kb1 = *(const bf16x8*)&Ks[ni * 16 + l15][32 + quad * 8];
        f32x4 z = {};
        z = __builtin_amdgcn_mfma_f32_16x16x32_bf16(qf0, kb0, z, 0, 0, 0);
        z = __builtin_amdgcn_mfma_f32_16x16x32_bf16(qf1, kb1, z, 0, 0, 0);
        s[ni] = z;
      }
      // online softmax (per q-row; cols spread over the 16 lanes of a quad-row group)
#pragma unroll
      for (int r = 0; r < 4; r++) {
        const int row_g = q0 + w * 16 + quad * 4 + r;
        float mx = -1e30f;
#pragma unroll
        for (int ni = 0; ni < 4; ni++) {
          const int col_g = kv0 + ni * 16 + l15;
          float sv = s[ni][r];
          sv = (col_g <= row_g) ? sv : -1e30f;
          s[ni][r] = sv;
          mx = fmaxf(mx, sv);
        }
        mx = fmaxf(mx, __shfl_xor(mx, 1));
        mx = fmaxf(mx, __shfl_xor(mx, 2));
        mx = fmaxf(mx, __shfl_xor(mx, 4));
        mx = fmaxf(mx, __shfl_xor(mx, 8));
        const float mnew = fmaxf(m_i[r], mx);
        alpha[r] = __expf(m_i[r] - mnew);
        m_i[r] = mnew;
        float rs = 0.f;
#pragma unroll
        for (int ni = 0; ni < 4; ni++) {
          const float px = __expf(s[ni][r] - mnew);
          s[ni][r] = px;
          rs += px;
        }
        rs += __shfl_xor(rs, 1);
        rs += __shfl_xor(rs, 2);
        rs += __shfl_xor(rs, 4);
        rs += __shfl_xor(rs, 8);
        l_i[r] = l_i[r] * alpha[r] + rs;
      }
      // P: MFMA C-layout -> per-wave LDS -> A-layout. Intra-wave only: no block barrier
      // needed; compiler orders ds_write->ds_read with lgkmcnt.
#pragma unroll
      for (int ni = 0; ni < 4; ni++)
#pragma unroll
        for (int r = 0; r < 4; r++)
          Ps[w][quad * 4 + r][ni * 16 + l15] = f2bf(s[ni][r]);
      // rescale O by alpha (row = quad*4+reg)
#pragma unroll
      for (int nd = 0; nd < 4; nd++)
#pragma unroll
        for (int r = 0; r < 4; r++)
          o[nd][r] *= alpha[r];
      // O += P @ V : A[m=qrow][k=kv], B[k=kv][n=d]
      const bf16x8 pa0 = *(const bf16x8*)&Ps[w][l15][quad * 8];
      const bf16x8 pa1 = *(const bf16x8*)&Ps[w][l15][32 + quad * 8];
#pragma unroll
      for (int nd = 0; nd < 4; nd++) {
        const bf16x8 vb0 = *(const bf16x8*)&Vs[nd * 16 + l15][quad * 8];
        const bf16x8 vb1 = *(const bf16x8*)&Vs[nd * 16 + l15][32 + quad * 8];
        o[nd] = __builtin_amdgcn_mfma_f32_16x16x32_bf16(pa0, vb0, o[nd], 0, 0, 0);
        o[nd] = __builtin_amdgcn_mfma_f32_16x16x32_bf16(pa1, vb1, o[nd], 0, 0, 0);
      }
    }
    // epilogue: normalize and write [B,T,H*D]
#pragma unroll
    for (int nd = 0; nd < 4; nd++)
#pragma unroll
      for (int r = 0; r < 4; r++) {
        const int row_g = q0 + w * 16 + quad * 4 + r;
        const size_t mg = (size_t)b * TT + row_g;
        AO[mg * CE + h * 64 + nd * 16 + l15] = f2bf(o[nd][r] / l_i[r]);
      }
  }
}

extern "C" void kernel_launch(void* const* d_in, const int* in_sizes, int n_in,
                              void* d_out, int out_size, void* d_ws, size_t ws_size,
                              hipStream_t stream) {
  const float* x     = (const float*)d_in[0];  // [4,2048,1024] f32
  const float* w_qkv = (const float*)d_in[1];  // [1024,3072] f32
  const float* w_out = (const float*)d_in[2];  // [1024,1024] f32
  const float* b_out = (const float*)d_in[3];  // [1024] f32
  float* out = (float*)d_out;                  // [4,2048,1024] f32

  unsigned short* ws  = (unsigned short*)d_ws;
  unsigned short* Xb  = ws;                                  // x bf16 [8192][1024]
  unsigned short* Wt1 = Xb  + (size_t)MM * CE;               // w_qkv^T  [3072][1024]
  unsigned short* Wt2 = Wt1 + (size_t)3072 * 1024;           // w_out^T  [1024][1024]
  unsigned short* Qb  = Wt2 + (size_t)1024 * 1024;           // [BH][T][64]
  unsigned short* Kb  = Qb  + (size_t)8388608;               // [BH][T][64]
  unsigned short* Vtb = Kb  + (size_t)8388608;               // [BH][64][T]
  unsigned short* AO  = Vtb + (size_t)8388608;               // [M][1024] bf16

  convert_x     <<<dim3(8192), 256, 0, stream>>>(x, Xb);
  transpose_conv<<<dim3(96, 32), 256, 0, stream>>>(w_qkv, Wt1, 1024, 3072);
  transpose_conv<<<dim3(32, 32), 256, 0, stream>>>(w_out, Wt2, 1024, 1024);
  gemm_qkv  <<<dim3(24, 64), 256, 0, stream>>>(Xb, Wt1, Qb, Kb, Vtb);
  flash_attn<<<dim3(16, 64), 256, 0, stream>>>(Qb, Kb, Vtb, AO);
  gemm_out  <<<dim3(8, 64), 256, 0, stream>>>(AO, Wt2, b_out, out);
}